// Round 8
// baseline (96.600 us; speedup 1.0000x reference)
//
#include <hip/hip_runtime.h>
#include <hip/hip_bf16.h>
#include <hip/hip_fp16.h>

#define B_    4096
#define ARITY 6
#define EMB   100
#define NF    200
#define FC    1200
#define NROWS (B_*ARITY)      // 24576
#define MPAD  (B_*8)          // 32768 padded M rows (8 per batch, 2 sentinel)
#define NPAD  2432            // N rows of W_h (A/C pairs interleaved)
#define NT3   (NPAD/32)       // 76 tiles of 32 N-rows
#define BN_EPS 1e-5f
#define KP    224
#define SENT  32768.0f

typedef _Float16 half8 __attribute__((ext_vector_type(8)));
typedef float f32x4 __attribute__((ext_vector_type(4)));

// ws float offsets
#define MRAW_OFF 0              // m_raw f16 [24576][200] -> 2,457,600 f
#define WH_OFF   2457600        // W_h f16 [2432][224]    ->   272,384 f
#define WT_OFF   2729984        // wT  f16 [7][2][224][32] ->   50,176 f
#define STAT_OFF 2780160        // gshad[16][400] + scale[200] + shift[200]

__device__ __forceinline__ void gload16(const void* g, void* l) {
    __builtin_amdgcn_global_load_lds(
        (const __attribute__((address_space(1))) void*)g,
        (__attribute__((address_space(3))) void*)l, 16, 0, 0);
}

__device__ __forceinline__ float4 ld4(const float* rr, const float* vr, int e) {
    if (e < EMB)        return *(const float4*)&rr[e];
    else if (e < 2*EMB) return *(const float4*)&vr[e - EMB];
    float4 z = {0.f,0.f,0.f,0.f}; return z;
}

// ---------------- k0: weight prep + out init -------------------------------
// Swizzle: within each [row][32] f16 K-tile, 16B-slot s -> s ^ ((row>>1)&3).
// wT layout: [ks][part(hi/lo)][224 rows][32 cols] -- per-step contiguous.
#define K0_W1 (224*28)
#define K0_W2 (K0_W1 + NPAD*28)
#define K0_TOT (K0_W2 + B_)
__launch_bounds__(256)
__global__ void k0_prep(const float* __restrict__ cw, const float* __restrict__ gW,
                        const float* __restrict__ fb,
                        _Float16* __restrict__ wT,
                        _Float16* __restrict__ W_h, float* __restrict__ out)
{
    int id = blockIdx.x * 256 + threadIdx.x;
    if (id < K0_W1) {
        int f = id / 28, s = id - f*28;
        int ks = s >> 2, ls = s & 3, key = (f >> 1) & 3;
        int off = ks*14336 + f*32 + ((ls ^ key)*8);
        half8 h, l;
        #pragma unroll
        for (int j = 0; j < 8; ++j) {
            int k = s*8 + j;
            float v = (f < NF && k < NF) ? cw[f*NF + k] : 0.f;
            _Float16 hi = (_Float16)v;
            h[j] = hi; l[j] = (_Float16)(v - (float)hi);
        }
        *(half8*)&wT[off] = h;
        *(half8*)&wT[off + 7168] = l;
    } else if (id < K0_W2) {
        int id2 = id - K0_W1;
        int n = id2 / 28, s = id2 - n*28;
        int o = n >> 1, hf = n & 1;
        int tile = s >> 2, ls = s & 3, key = (n >> 1) & 3;
        int col = tile*32 + (ls ^ key)*8;
        half8 h;
        #pragma unroll
        for (int j = 0; j < 8; ++j) {
            int k = s*8 + j;
            float v = 0.f;
            if (k < NF && n < 2*FC) v = gW[(size_t)o*400 + hf*200 + k];
            if (k == NF) v = SENT;           // sentinel column
            h[j] = (_Float16)v;
        }
        *(half8*)&W_h[(size_t)n*KP + col] = h;
    } else if (id < K0_TOT) {
        out[id - K0_W2] = fb[0];
    }
}

// ---------------- k1: gather + split-f16 MFMA conv + stats -----------------
// Grid 768 (M-tile 32), 4 waves 2Mx2N. A (hi/lo) built once in LDS, hoisted
// to regs. W staged per K-step from wT via ring-2 gload_lds, counted vmcnt.
// Ring-2 stage-at-bottom REQUIRES the fence: lgkmcnt(0) + sched_barrier +
// s_barrier + sched_barrier before STAGE_W (stage overwrites the buffer this
// wave just ds_read; bare s_barrier has no compiler memory semantics).
// LDS: ring 2x28672 @0 | s_sum @57344 | s_sq @58144 | s_ri @58944 | s_vi @59072
__launch_bounds__(256)
__global__ void k1_mfma(const int* __restrict__ x,
                        const float* __restrict__ er,
                        const float* __restrict__ ev,
                        const _Float16* __restrict__ wT,
                        const float* __restrict__ cb,
                        _Float16* __restrict__ m_raw,
                        float* __restrict__ gshad)
{
    __shared__ __align__(16) char smem[59200];
    float* s_sum = (float*)(smem + 57344);
    float* s_sq  = (float*)(smem + 58144);
    int*   s_ri  = (int*)(smem + 58944);
    int*   s_vi  = (int*)(smem + 59072);

    const int t = threadIdx.x, lane = t & 63, wave = t >> 6;
    const int wm = wave >> 1, wn = wave & 1;
    const int R0 = blockIdx.x * 32;
    const int q = lane >> 4, cx = lane & 15;
    const int rdsw = (q ^ ((cx >> 1) & 3)) * 8;

    if (t < 32) {
        int R = R0 + t, b = R / ARITY, a = R - b * ARITY;
        bool is64 = ((x[1] | x[3] | x[5] | x[7]) == 0);
        int base = b * (2*ARITY) + 2*a;
        s_ri[t] = is64 ? x[2*base]     : x[base];
        s_vi[t] = is64 ? x[2*base + 2] : x[base + 1];
    }
    if (t < NF) { s_sum[t] = 0.f; s_sq[t] = 0.f; }
    __syncthreads();

    // ---- build A panel (32 rows x 224, hi+lo) in buf0, swizzled ----
    {
        _Float16* s_ahi = (_Float16*)smem;          // 32x224
        _Float16* s_alo = s_ahi + 7168;
        for (int c = t; c < 896; c += 256) {
            int row = c / 28, s = c - row*28;
            int key = (row >> 1) & 3;
            int col = (s >> 2)*32 + ((s & 3) ^ key)*8;
            const float* rr = er + (size_t)s_ri[row] * EMB;
            const float* vr = ev + (size_t)s_vi[row] * EMB;
            int e0 = s*8;
            float4 v0 = ld4(rr, vr, e0);
            float4 v1 = ld4(rr, vr, e0 + 4);
            half8 hi, lo;
            hi[0]=(_Float16)v0.x; lo[0]=(_Float16)(v0.x-(float)hi[0]);
            hi[1]=(_Float16)v0.y; lo[1]=(_Float16)(v0.y-(float)hi[1]);
            hi[2]=(_Float16)v0.z; lo[2]=(_Float16)(v0.z-(float)hi[2]);
            hi[3]=(_Float16)v0.w; lo[3]=(_Float16)(v0.w-(float)hi[3]);
            hi[4]=(_Float16)v1.x; lo[4]=(_Float16)(v1.x-(float)hi[4]);
            hi[5]=(_Float16)v1.y; lo[5]=(_Float16)(v1.y-(float)hi[5]);
            hi[6]=(_Float16)v1.z; lo[6]=(_Float16)(v1.z-(float)hi[6]);
            hi[7]=(_Float16)v1.w; lo[7]=(_Float16)(v1.w-(float)hi[7]);
            *(half8*)&s_ahi[row*KP + col] = hi;
            *(half8*)&s_alo[row*KP + col] = lo;
        }
    }
    __syncthreads();

    // ---- hoist A fragments (1 mf x 7 ks, hi+lo) to registers ----
    f32x4 ah[7], al[7];
    {
        const _Float16* s_ahi = (const _Float16*)smem;
        const _Float16* s_alo = s_ahi + 7168;
        int arow = wm*16 + cx;
        #pragma unroll
        for (int ks = 0; ks < 7; ++ks) {
            ah[ks] = *(const f32x4*)&s_ahi[arow*KP + ks*32 + rdsw];
            al[ks] = *(const f32x4*)&s_alo[arow*KP + ks*32 + rdsw];
            asm volatile("" : "+v"(ah[ks]), "+v"(al[ks]));
        }
    }
    __syncthreads();   // A reads done; drains all vmem -> counts exact below

    #define STAGE_W(KS_, BUF_) do {                                          \
        const char* _src = (const char*)wT + (size_t)(KS_) * 28672;          \
        char* _dst = smem + (BUF_) * 28672;                                  \
        _Pragma("unroll")                                                    \
        for (int _i = 0; _i < 7; ++_i) {                                     \
            int _j = wave + 4*_i;                                            \
            gload16(_src + (size_t)(_j*64 + lane)*16, _dst + _j*1024);       \
        }                                                                    \
    } while (0)

    STAGE_W(0, 0);
    STAGE_W(1, 1);

    f32x4 acc[7];
    #pragma unroll
    for (int nf = 0; nf < 7; ++nf) acc[nf] = (f32x4){0.f,0.f,0.f,0.f};

    for (int ks = 0; ks < 7; ++ks) {
        if (ks < 6) asm volatile("s_waitcnt vmcnt(7)" ::: "memory");
        else        asm volatile("s_waitcnt vmcnt(0)" ::: "memory");
        __builtin_amdgcn_s_barrier();
        __builtin_amdgcn_sched_barrier(0);

        const _Float16* wb = (const _Float16*)(smem + (ks & 1) * 28672);
        #pragma unroll
        for (int nf = 0; nf < 7; ++nf) {
            int rb = (wn*112 + nf*16 + cx)*32 + rdsw;
            half8 bh = *(const half8*)&wb[rb];
            half8 bl = *(const half8*)&wb[7168 + rb];
            acc[nf] = __builtin_amdgcn_mfma_f32_16x16x32_f16(
                __builtin_bit_cast(half8, ah[ks]), bh, acc[nf], 0,0,0);
            acc[nf] = __builtin_amdgcn_mfma_f32_16x16x32_f16(
                __builtin_bit_cast(half8, ah[ks]), bl, acc[nf], 0,0,0);
            acc[nf] = __builtin_amdgcn_mfma_f32_16x16x32_f16(
                __builtin_bit_cast(half8, al[ks]), bh, acc[nf], 0,0,0);
        }
        // FENCE: own ds_reads complete, all waves past them, nothing moves
        // across -- only then may the stage overwrite this buffer.
        asm volatile("s_waitcnt lgkmcnt(0)" ::: "memory");
        __builtin_amdgcn_sched_barrier(0);
        __builtin_amdgcn_s_barrier();
        __builtin_amdgcn_sched_barrier(0);
        if (ks + 2 < 7) STAGE_W(ks + 2, ks & 1);
    }

    // epilogue: +bias, write m_raw (f16), block stats
    #pragma unroll
    for (int nf = 0; nf < 7; ++nf) {
        int f = wn*112 + nf*16 + cx;
        bool valid = (f < NF);
        float bias = valid ? cb[f] : 0.f;
        float ps = 0.f, pq = 0.f;
        #pragma unroll
        for (int reg = 0; reg < 4; ++reg) {
            float vv = acc[nf][reg] + bias;
            if (valid) {
                int R = R0 + wm*16 + q*4 + reg;
                m_raw[(size_t)R*NF + f] = (_Float16)vv;
                ps += vv; pq += vv*vv;
            }
        }
        ps += __shfl_xor(ps, 16); ps += __shfl_xor(ps, 32);
        pq += __shfl_xor(pq, 16); pq += __shfl_xor(pq, 32);
        if (valid && q == 0) { atomicAdd(&s_sum[f], ps); atomicAdd(&s_sq[f], pq); }
    }
    __syncthreads();
    if (t < NF) {
        float* g = gshad + (blockIdx.x & 15) * 400;
        atomicAdd(&g[t], s_sum[t]);
        atomicAdd(&g[t + 200], s_sq[t]);
    }
}

// ---------------- k2: finalize BN scale/shift ------------------------------
__global__ void k2_stats(const float* __restrict__ gshad,
                         const float* __restrict__ gamma,
                         const float* __restrict__ beta,
                         float* __restrict__ scale,
                         float* __restrict__ shift)
{
    int t = threadIdx.x;
    if (t < NF) {
        float s = 0.f, qq = 0.f;
        #pragma unroll
        for (int c = 0; c < 16; ++c) { s += gshad[c*400 + t]; qq += gshad[c*400 + 200 + t]; }
        float inv = 1.0f / (float)NROWS;
        float mu  = s * inv;
        float var = qq * inv - mu*mu;
        float rs  = rsqrtf(var + BN_EPS);
        float sc  = rs * gamma[t];
        scale[t] = sc;
        shift[t] = beta[t] - mu*sc;
    }
}

// ---------------- k3: fused BN + A-resident MFMA + min + final -------------
// Grid 512 (2 blocks/CU), 4 waves, block = 64 padded M rows (8 batches).
// 76 N-tiles of 32 rows, ring-4 LDS staged via gload_lds, counted vmcnt.
// Ring-4 stage-at-top is reorder-safe: stage target is always >=3 (mod 4)
// buffers away from any buffer still being read.
// LDS: ring 4x14336 @0 | gbfw2 @57344 (9728B) | scsh @67072 (1792B) = 68864
__launch_bounds__(256)
__global__ void k3_mfma(const _Float16* __restrict__ m_raw,
                        const float* __restrict__ scale,
                        const float* __restrict__ shift,
                        const _Float16* __restrict__ W_h,
                        const float* __restrict__ gb,
                        const float* __restrict__ fW,
                        float* __restrict__ out)
{
    __shared__ __align__(16) char smem[68864];
    float2* gbfw2 = (float2*)(smem + 57344);
    float*  scsh  = (float*)(smem + 67072);

    const int t = threadIdx.x, lane = t & 63, wave = t >> 6;
    const int wm = wave >> 1, wn = wave & 1;
    const int q = lane >> 4, cx = lane & 15;
    const int rdsw = (q ^ ((cx >> 1) & 3)) * 8;

    // ---- prologue: constant tables ----
    for (int i = t; i < 224; i += 256) {
        scsh[i]       = (i < NF) ? scale[i] : 0.f;
        scsh[224 + i] = (i < NF) ? shift[i] : 0.f;
    }
    for (int i = t; i < 1216; i += 256) {
        float g = (i < FC) ? gb[i] : 0.f;
        float f = (i < FC) ? fW[i] : 0.f;
        gbfw2[i] = make_float2(g, f);
    }
    __syncthreads();

    // ---- build padded+swizzled A panel (64 rows x 224 f16) in bufs 0-1 ----
    {
        _Float16* sa = (_Float16*)smem;
        for (int c = t; c < 1792; c += 256) {          // 64 rows x 28 chunks
            int Rp = c / 28, s = c - Rp*28;
            int a = Rp & 7, b = Rp >> 3;
            int key = (Rp >> 1) & 3;
            int col = (s >> 2)*32 + ((s & 3) ^ key)*8;
            half8 o;
            #pragma unroll
            for (int j = 0; j < 8; ++j) o[j] = (_Float16)0.f;
            if (a < ARITY && s < 25) {
                int R = (blockIdx.x*8 + b)*ARITY + a;
                half8 in = *(const half8*)&m_raw[(size_t)R*NF + s*8];
                #pragma unroll
                for (int j = 0; j < 8; ++j) {
                    int k = s*8 + j;
                    o[j] = (_Float16)fmaxf((float)in[j]*scsh[k] + scsh[224+k], 0.f);
                }
            } else if (a >= ARITY && s == 25) {
                o[0] = (_Float16)1.0f;                 // k==200 sentinel unit
            }
            *(half8*)&sa[Rp*KP + col] = o;
        }
    }
    __syncthreads();

    // ---- hoist A fragments (2 mf x 7 ks) to registers ----
    f32x4 av[2][7];
    {
        const _Float16* sa = (const _Float16*)smem;
        #pragma unroll
        for (int mf = 0; mf < 2; ++mf) {
            int row = wm*32 + mf*16 + cx;
            #pragma unroll
            for (int ks = 0; ks < 7; ++ks) {
                av[mf][ks] = *(const f32x4*)&sa[row*KP + ks*32 + rdsw];
                asm volatile("" : "+v"(av[mf][ks]));
            }
        }
    }
    __syncthreads();   // A reads complete; drains vmcnt -> counts exact

    // ring stage: tile = 32 N-rows x 224 K = 14336 B = 14 chunks of 1KB.
    // waves 0,1 stage 4 chunks; waves 2,3 stage 3.
    #define STAGE_B3(NT_, BUF_) do {                                         \
        const char* _src = (const char*)W_h + (size_t)(NT_) * 14336;         \
        char* _dst = smem + (BUF_) * 14336;                                  \
        _Pragma("unroll")                                                    \
        for (int _i = 0; _i < 4; ++_i) {                                     \
            int _j = wave + 4*_i;                                            \
            if (_j < 14)                                                     \
                gload16(_src + (size_t)(_j*64 + lane)*16, _dst + _j*1024);   \
        }                                                                    \
    } while (0)

    STAGE_B3(0, 0);
    STAGE_B3(1, 1);

    float preg[2] = {0.f, 0.f};

    for (int nt = 0; nt < NT3; ++nt) {
        if (nt + 2 < NT3) {
            STAGE_B3(nt + 2, (nt + 2) & 3);
            if (wave < 2) asm volatile("s_waitcnt vmcnt(8)" ::: "memory");
            else          asm volatile("s_waitcnt vmcnt(6)" ::: "memory");
        } else if (nt + 2 == NT3) {
            if (wave < 2) asm volatile("s_waitcnt vmcnt(4)" ::: "memory");
            else          asm volatile("s_waitcnt vmcnt(3)" ::: "memory");
        } else {
            asm volatile("s_waitcnt vmcnt(0)" ::: "memory");
        }
        __builtin_amdgcn_s_barrier();
        __builtin_amdgcn_sched_barrier(0);

        const _Float16* cur = (const _Float16*)(smem + (nt & 3) * 14336);

        f32x4 acc[2];
        acc[0] = (f32x4){0.f,0.f,0.f,0.f};
        acc[1] = (f32x4){0.f,0.f,0.f,0.f};

        #pragma unroll
        for (int ks = 0; ks < 7; ++ks) {
            f32x4 bv = *(const f32x4*)&cur[(wn*16 + cx)*KP + ks*32 + rdsw];
            #pragma unroll
            for (int mf = 0; mf < 2; ++mf)
                acc[mf] = __builtin_amdgcn_mfma_f32_16x16x32_f16(
                    __builtin_bit_cast(half8, av[mf][ks]),
                    __builtin_bit_cast(half8, bv), acc[mf], 0, 0, 0);
        }

        // register epilogue: min over 8 rows, A+C pair, relu, dot with fW
        #pragma unroll
        for (int mf = 0; mf < 2; ++mf) {
            f32x4 a4 = acc[mf];
            float v = fminf(fminf(a4[0], a4[1]), fminf(a4[2], a4[3]));
            v = fminf(v, __shfl_xor(v, 16));        // min over q-pair (8 rows)
            float vp = v + __shfl_xor(v, 1);        // A + C halves
            int o = (nt*32 + wn*16 + cx) >> 1;
            float2 gf = gbfw2[o];                   // LDS, not vmem
            float val = fmaxf(vp + gf.x, 0.f) * gf.y;
            if (((q & 1) == 0) && ((cx & 1) == 0)) preg[mf] += val;
        }
        // no trailing barrier: buf[nt&3] restaged only at iter nt+2, after
        // barrier(nt+1) -> all waves done computing tile nt.
    }

    #pragma unroll
    for (int mf = 0; mf < 2; ++mf) {
        float v = preg[mf];
        v += __shfl_xor(v, 2);
        v += __shfl_xor(v, 4);
        v += __shfl_xor(v, 8);
        if (cx == 0 && (q & 1) == 0) {
            int bb = blockIdx.x*8 + wm*4 + mf*2 + (q >> 1);
            atomicAdd(&out[bb], v);
        }
    }
}

extern "C" void kernel_launch(void* const* d_in, const int* in_sizes, int n_in,
                              void* d_out, int out_size, void* d_ws, size_t ws_size,
                              hipStream_t stream)
{
    const int*   x   = (const int*)  d_in[0];
    const float* er  = (const float*)d_in[1];
    const float* ev  = (const float*)d_in[2];
    const float* cw  = (const float*)d_in[3];
    const float* cb  = (const float*)d_in[4];
    const float* gam = (const float*)d_in[5];
    const float* bet = (const float*)d_in[6];
    const float* gW  = (const float*)d_in[7];
    const float* gb  = (const float*)d_in[8];
    const float* fW  = (const float*)d_in[9];
    const float* fb  = (const float*)d_in[10];

    float* ws = (float*)d_ws;
    _Float16* m_raw = (_Float16*)(ws + MRAW_OFF);
    _Float16* W_h   = (_Float16*)(ws + WH_OFF);
    _Float16* wT    = (_Float16*)(ws + WT_OFF);
    float* gshad    = ws + STAT_OFF;
    float* scale    = gshad + 6400;
    float* shift    = scale + 200;
    float* out      = (float*)d_out;

    (void)hipMemsetAsync(gshad, 0, 16*400*sizeof(float), stream);

    k0_prep<<<(K0_TOT + 255)/256, 256, 0, stream>>>(cw, gW, fb, wT, W_h, out);
    k1_mfma<<<NROWS/32, 256, 0, stream>>>(x, er, ev, wT, cb, m_raw, gshad);
    k2_stats<<<1, 256, 0, stream>>>(gshad, gam, bet, scale, shift);
    k3_mfma<<<MPAD/64, 256, 0, stream>>>(m_raw, scale, shift, W_h, gb, fW, out);
}

// Round 9
// 90.042 us; speedup vs baseline: 1.0728x; 1.0728x over previous
//
#include <hip/hip_runtime.h>
#include <hip/hip_bf16.h>
#include <hip/hip_fp16.h>

#define B_    4096
#define ARITY 6
#define EMB   100
#define NF    200
#define FC    1200
#define NROWS (B_*ARITY)      // 24576
#define MPAD  (B_*8)          // 32768 padded M rows (8 per batch, 2 sentinel)
#define NPAD  2432            // N rows of W_h (A/C pairs interleaved)
#define BN_EPS 1e-5f
#define KP    224
#define SENT  32768.0f
#define NTW   (NPAD/4/16)     // 38 tiles of 16 N-rows per wave

typedef _Float16 half8 __attribute__((ext_vector_type(8)));
typedef float f32x4 __attribute__((ext_vector_type(4)));

// ws float offsets
#define MRAW_OFF 0              // m_raw f16 [24576][200] -> 2,457,600 f
#define WH_OFF   2457600        // W_h f16 [2432][224]    ->   272,384 f
#define WT_OFF   2729984        // wT  f16 [7][2][224][32] ->   50,176 f
#define STAT_OFF 2780160        // gshad[16][400] + scale[200] + shift[200]

__device__ __forceinline__ void gload16(const void* g, void* l) {
    __builtin_amdgcn_global_load_lds(
        (const __attribute__((address_space(1))) void*)g,
        (__attribute__((address_space(3))) void*)l, 16, 0, 0);
}

__device__ __forceinline__ float4 ld4(const float* rr, const float* vr, int e) {
    if (e < EMB)        return *(const float4*)&rr[e];
    else if (e < 2*EMB) return *(const float4*)&vr[e - EMB];
    float4 z = {0.f,0.f,0.f,0.f}; return z;
}

// ---------------- k0: weight prep + out init -------------------------------
// Swizzle: within each [row][32] f16 K-tile, 16B-slot s -> s ^ ((row>>1)&3).
// wT layout: [ks][part(hi/lo)][224 rows][32 cols] -- per-step contiguous.
#define K0_W1 (224*28)
#define K0_W2 (K0_W1 + NPAD*28)
#define K0_TOT (K0_W2 + B_)
__launch_bounds__(256)
__global__ void k0_prep(const float* __restrict__ cw, const float* __restrict__ gW,
                        const float* __restrict__ fb,
                        _Float16* __restrict__ wT,
                        _Float16* __restrict__ W_h, float* __restrict__ out)
{
    int id = blockIdx.x * 256 + threadIdx.x;
    if (id < K0_W1) {
        int f = id / 28, s = id - f*28;
        int ks = s >> 2, ls = s & 3, key = (f >> 1) & 3;
        int off = ks*14336 + f*32 + ((ls ^ key)*8);
        half8 h, l;
        #pragma unroll
        for (int j = 0; j < 8; ++j) {
            int k = s*8 + j;
            float v = (f < NF && k < NF) ? cw[f*NF + k] : 0.f;
            _Float16 hi = (_Float16)v;
            h[j] = hi; l[j] = (_Float16)(v - (float)hi);
        }
        *(half8*)&wT[off] = h;
        *(half8*)&wT[off + 7168] = l;
    } else if (id < K0_W2) {
        int id2 = id - K0_W1;
        int n = id2 / 28, s = id2 - n*28;
        int o = n >> 1, hf = n & 1;
        int tile = s >> 2, ls = s & 3, key = (n >> 1) & 3;
        int col = tile*32 + (ls ^ key)*8;
        half8 h;
        #pragma unroll
        for (int j = 0; j < 8; ++j) {
            int k = s*8 + j;
            float v = 0.f;
            if (k < NF && n < 2*FC) v = gW[(size_t)o*400 + hf*200 + k];
            if (k == NF) v = SENT;           // sentinel column
            h[j] = (_Float16)v;
        }
        *(half8*)&W_h[(size_t)n*KP + col] = h;
    } else if (id < K0_TOT) {
        out[id - K0_W2] = fb[0];
    }
}

// ---------------- k1: gather + split-f16 MFMA conv + stats -----------------
// (unchanged from round 8 -- passing, fenced ring-2)
__launch_bounds__(256)
__global__ void k1_mfma(const int* __restrict__ x,
                        const float* __restrict__ er,
                        const float* __restrict__ ev,
                        const _Float16* __restrict__ wT,
                        const float* __restrict__ cb,
                        _Float16* __restrict__ m_raw,
                        float* __restrict__ gshad)
{
    __shared__ __align__(16) char smem[59200];
    float* s_sum = (float*)(smem + 57344);
    float* s_sq  = (float*)(smem + 58144);
    int*   s_ri  = (int*)(smem + 58944);
    int*   s_vi  = (int*)(smem + 59072);

    const int t = threadIdx.x, lane = t & 63, wave = t >> 6;
    const int wm = wave >> 1, wn = wave & 1;
    const int R0 = blockIdx.x * 32;
    const int q = lane >> 4, cx = lane & 15;
    const int rdsw = (q ^ ((cx >> 1) & 3)) * 8;

    if (t < 32) {
        int R = R0 + t, b = R / ARITY, a = R - b * ARITY;
        bool is64 = ((x[1] | x[3] | x[5] | x[7]) == 0);
        int base = b * (2*ARITY) + 2*a;
        s_ri[t] = is64 ? x[2*base]     : x[base];
        s_vi[t] = is64 ? x[2*base + 2] : x[base + 1];
    }
    if (t < NF) { s_sum[t] = 0.f; s_sq[t] = 0.f; }
    __syncthreads();

    // ---- build A panel (32 rows x 224, hi+lo) in buf0, swizzled ----
    {
        _Float16* s_ahi = (_Float16*)smem;          // 32x224
        _Float16* s_alo = s_ahi + 7168;
        for (int c = t; c < 896; c += 256) {
            int row = c / 28, s = c - row*28;
            int key = (row >> 1) & 3;
            int col = (s >> 2)*32 + ((s & 3) ^ key)*8;
            const float* rr = er + (size_t)s_ri[row] * EMB;
            const float* vr = ev + (size_t)s_vi[row] * EMB;
            int e0 = s*8;
            float4 v0 = ld4(rr, vr, e0);
            float4 v1 = ld4(rr, vr, e0 + 4);
            half8 hi, lo;
            hi[0]=(_Float16)v0.x; lo[0]=(_Float16)(v0.x-(float)hi[0]);
            hi[1]=(_Float16)v0.y; lo[1]=(_Float16)(v0.y-(float)hi[1]);
            hi[2]=(_Float16)v0.z; lo[2]=(_Float16)(v0.z-(float)hi[2]);
            hi[3]=(_Float16)v0.w; lo[3]=(_Float16)(v0.w-(float)hi[3]);
            hi[4]=(_Float16)v1.x; lo[4]=(_Float16)(v1.x-(float)hi[4]);
            hi[5]=(_Float16)v1.y; lo[5]=(_Float16)(v1.y-(float)hi[5]);
            hi[6]=(_Float16)v1.z; lo[6]=(_Float16)(v1.z-(float)hi[6]);
            hi[7]=(_Float16)v1.w; lo[7]=(_Float16)(v1.w-(float)hi[7]);
            *(half8*)&s_ahi[row*KP + col] = hi;
            *(half8*)&s_alo[row*KP + col] = lo;
        }
    }
    __syncthreads();

    // ---- hoist A fragments (1 mf x 7 ks, hi+lo) to registers ----
    f32x4 ah[7], al[7];
    {
        const _Float16* s_ahi = (const _Float16*)smem;
        const _Float16* s_alo = s_ahi + 7168;
        int arow = wm*16 + cx;
        #pragma unroll
        for (int ks = 0; ks < 7; ++ks) {
            ah[ks] = *(const f32x4*)&s_ahi[arow*KP + ks*32 + rdsw];
            al[ks] = *(const f32x4*)&s_alo[arow*KP + ks*32 + rdsw];
            asm volatile("" : "+v"(ah[ks]), "+v"(al[ks]));
        }
    }
    __syncthreads();   // A reads done; drains all vmem -> counts exact below

    #define STAGE_W(KS_, BUF_) do {                                          \
        const char* _src = (const char*)wT + (size_t)(KS_) * 28672;          \
        char* _dst = smem + (BUF_) * 28672;                                  \
        _Pragma("unroll")                                                    \
        for (int _i = 0; _i < 7; ++_i) {                                     \
            int _j = wave + 4*_i;                                            \
            gload16(_src + (size_t)(_j*64 + lane)*16, _dst + _j*1024);       \
        }                                                                    \
    } while (0)

    STAGE_W(0, 0);
    STAGE_W(1, 1);

    f32x4 acc[7];
    #pragma unroll
    for (int nf = 0; nf < 7; ++nf) acc[nf] = (f32x4){0.f,0.f,0.f,0.f};

    for (int ks = 0; ks < 7; ++ks) {
        if (ks < 6) asm volatile("s_waitcnt vmcnt(7)" ::: "memory");
        else        asm volatile("s_waitcnt vmcnt(0)" ::: "memory");
        __builtin_amdgcn_s_barrier();
        __builtin_amdgcn_sched_barrier(0);

        const _Float16* wb = (const _Float16*)(smem + (ks & 1) * 28672);
        #pragma unroll
        for (int nf = 0; nf < 7; ++nf) {
            int rb = (wn*112 + nf*16 + cx)*32 + rdsw;
            half8 bh = *(const half8*)&wb[rb];
            half8 bl = *(const half8*)&wb[7168 + rb];
            acc[nf] = __builtin_amdgcn_mfma_f32_16x16x32_f16(
                __builtin_bit_cast(half8, ah[ks]), bh, acc[nf], 0,0,0);
            acc[nf] = __builtin_amdgcn_mfma_f32_16x16x32_f16(
                __builtin_bit_cast(half8, ah[ks]), bl, acc[nf], 0,0,0);
            acc[nf] = __builtin_amdgcn_mfma_f32_16x16x32_f16(
                __builtin_bit_cast(half8, al[ks]), bh, acc[nf], 0,0,0);
        }
        // FENCE: own ds_reads complete, all waves past them, nothing moves
        // across -- only then may the stage overwrite this buffer.
        asm volatile("s_waitcnt lgkmcnt(0)" ::: "memory");
        __builtin_amdgcn_sched_barrier(0);
        __builtin_amdgcn_s_barrier();
        __builtin_amdgcn_sched_barrier(0);
        if (ks + 2 < 7) STAGE_W(ks + 2, ks & 1);
    }

    // epilogue: +bias, write m_raw (f16), block stats
    #pragma unroll
    for (int nf = 0; nf < 7; ++nf) {
        int f = wn*112 + nf*16 + cx;
        bool valid = (f < NF);
        float bias = valid ? cb[f] : 0.f;
        float ps = 0.f, pq = 0.f;
        #pragma unroll
        for (int reg = 0; reg < 4; ++reg) {
            float vv = acc[nf][reg] + bias;
            if (valid) {
                int R = R0 + wm*16 + q*4 + reg;
                m_raw[(size_t)R*NF + f] = (_Float16)vv;
                ps += vv; pq += vv*vv;
            }
        }
        ps += __shfl_xor(ps, 16); ps += __shfl_xor(ps, 32);
        pq += __shfl_xor(pq, 16); pq += __shfl_xor(pq, 32);
        if (valid && q == 0) { atomicAdd(&s_sum[f], ps); atomicAdd(&s_sq[f], pq); }
    }
    __syncthreads();
    if (t < NF) {
        float* g = gshad + (blockIdx.x & 15) * 400;
        atomicAdd(&g[t], s_sum[t]);
        atomicAdd(&g[t + 200], s_sq[t]);
    }
}

// ---------------- k2: finalize BN scale/shift ------------------------------
__global__ void k2_stats(const float* __restrict__ gshad,
                         const float* __restrict__ gamma,
                         const float* __restrict__ beta,
                         float* __restrict__ scale,
                         float* __restrict__ shift)
{
    int t = threadIdx.x;
    if (t < NF) {
        float s = 0.f, qq = 0.f;
        #pragma unroll
        for (int c = 0; c < 16; ++c) { s += gshad[c*400 + t]; qq += gshad[c*400 + 200 + t]; }
        float inv = 1.0f / (float)NROWS;
        float mu  = s * inv;
        float var = qq * inv - mu*mu;
        float rs  = rsqrtf(var + BN_EPS);
        float sc  = rs * gamma[t];
        scale[t] = sc;
        shift[t] = beta[t] - mu*sc;
    }
}

// ---------------- k3: WAVE-AUTONOMOUS MFMA + min + final -------------------
// Grid 512 (2 blocks/CU), 4 waves, block = 64 padded M rows (8 batches).
// Each wave: ALL 64 M rows (A frags 4mf x 7ks in 112 VGPR) x a PRIVATE
// quarter of the o-space (608 N-rows = 38 tiles of 16). Sum over o needs no
// inter-wave sync -> ZERO barriers in main loop. Per-wave ring-2 LDS buffer
// staged via gload_lds with per-wave counted vmcnt(7); lgkmcnt(0)+
// sched_barrier fence before overwriting the just-read buffer.
// LDS: ring 4 waves x 2 x 7168 @0 | gbfw2 @57344 (9728B) | scsh @67072 = 68864
__launch_bounds__(256)
__global__ void k3_mfma(const _Float16* __restrict__ m_raw,
                        const float* __restrict__ scale,
                        const float* __restrict__ shift,
                        const _Float16* __restrict__ W_h,
                        const float* __restrict__ gb,
                        const float* __restrict__ fW,
                        float* __restrict__ out)
{
    __shared__ __align__(16) char smem[68864];
    float2* gbfw2 = (float2*)(smem + 57344);
    float*  scsh  = (float*)(smem + 67072);

    const int t = threadIdx.x, lane = t & 63, wave = t >> 6;
    const int q = lane >> 4, cx = lane & 15;
    const int rdsw = (q ^ ((cx >> 1) & 3)) * 8;

    // ---- prologue: constant tables ----
    for (int i = t; i < 224; i += 256) {
        scsh[i]       = (i < NF) ? scale[i] : 0.f;
        scsh[224 + i] = (i < NF) ? shift[i] : 0.f;
    }
    for (int i = t; i < 1216; i += 256) {
        float g = (i < FC) ? gb[i] : 0.f;
        float f = (i < FC) ? fW[i] : 0.f;
        gbfw2[i] = make_float2(g, f);
    }
    __syncthreads();

    // ---- build padded+swizzled A panel (64 rows x 224 f16) at smem[0) ----
    {
        _Float16* sa = (_Float16*)smem;
        for (int c = t; c < 1792; c += 256) {          // 64 rows x 28 chunks
            int Rp = c / 28, s = c - Rp*28;
            int a = Rp & 7, b = Rp >> 3;
            int key = (Rp >> 1) & 3;
            int col = (s >> 2)*32 + ((s & 3) ^ key)*8;
            half8 o;
            #pragma unroll
            for (int j = 0; j < 8; ++j) o[j] = (_Float16)0.f;
            if (a < ARITY && s < 25) {
                int R = (blockIdx.x*8 + b)*ARITY + a;
                half8 in = *(const half8*)&m_raw[(size_t)R*NF + s*8];
                #pragma unroll
                for (int j = 0; j < 8; ++j) {
                    int k = s*8 + j;
                    o[j] = (_Float16)fmaxf((float)in[j]*scsh[k] + scsh[224+k], 0.f);
                }
            } else if (a >= ARITY && s == 25) {
                o[0] = (_Float16)1.0f;                 // k==200 sentinel unit
            }
            *(half8*)&sa[Rp*KP + col] = o;
        }
    }
    __syncthreads();

    // ---- hoist A fragments (4 mf x 7 ks) to registers: rows mf*16+cx ----
    f32x4 av[4][7];
    {
        const _Float16* sa = (const _Float16*)smem;
        #pragma unroll
        for (int mf = 0; mf < 4; ++mf) {
            int row = mf*16 + cx;
            #pragma unroll
            for (int ks = 0; ks < 7; ++ks) {
                av[mf][ks] = *(const f32x4*)&sa[row*KP + ks*32 + rdsw];
                asm volatile("" : "+v"(av[mf][ks]));
            }
        }
    }
    __syncthreads();   // HIP syncthreads drains vmcnt+lgkmcnt -> counts exact

    // ---- wave-private ring-2 staging over this wave's o-quarter ----
    const int nbase = wave * (NPAD/4);                 // 608 N-rows per wave
    const char* wsrc = (const char*)(W_h + (size_t)nbase * KP);
    char* wbuf = smem + wave * 14336;

    #define STAGE3(NT_) do {                                                 \
        const char* _s = wsrc + (size_t)(NT_) * 7168;                        \
        char* _d = wbuf + ((NT_) & 1) * 7168;                                \
        _Pragma("unroll")                                                    \
        for (int _i = 0; _i < 7; ++_i)                                       \
            gload16(_s + (size_t)(_i*64 + lane)*16, _d + _i*1024);           \
    } while (0)

    STAGE3(0);
    STAGE3(1);

    float preg[4] = {0.f, 0.f, 0.f, 0.f};

    for (int nt = 0; nt < NTW; ++nt) {
        if (nt + 1 < NTW) asm volatile("s_waitcnt vmcnt(7)" ::: "memory");
        else              asm volatile("s_waitcnt vmcnt(0)" ::: "memory");
        __builtin_amdgcn_sched_barrier(0);

        const _Float16* cur = (const _Float16*)(wbuf + (nt & 1) * 7168);

        f32x4 acc[4];
        #pragma unroll
        for (int mf = 0; mf < 4; ++mf) acc[mf] = (f32x4){0.f,0.f,0.f,0.f};

        #pragma unroll
        for (int ks = 0; ks < 7; ++ks) {
            f32x4 bv = *(const f32x4*)&cur[cx*KP + ks*32 + rdsw];
            #pragma unroll
            for (int mf = 0; mf < 4; ++mf)
                acc[mf] = __builtin_amdgcn_mfma_f32_16x16x32_f16(
                    __builtin_bit_cast(half8, av[mf][ks]),
                    __builtin_bit_cast(half8, bv), acc[mf], 0, 0, 0);
        }

        // FENCE (wave-local): own ds_reads of cur complete before the stage
        // below overwrites cur's buffer; nothing crosses the fence.
        asm volatile("s_waitcnt lgkmcnt(0)" ::: "memory");
        __builtin_amdgcn_sched_barrier(0);
        if (nt + 2 < NTW) STAGE3(nt + 2);

        // register epilogue (overlaps the stage's flight time):
        // min over 8 rows, A+C pair, relu, dot with fW
        #pragma unroll
        for (int mf = 0; mf < 4; ++mf) {
            f32x4 a4 = acc[mf];
            float v = fminf(fminf(a4[0], a4[1]), fminf(a4[2], a4[3]));
            v = fminf(v, __shfl_xor(v, 16));        // min over q-pair (8 rows)
            float vp = v + __shfl_xor(v, 1);        // A + C halves
            int o = (nbase + nt*16 + cx) >> 1;
            float2 gf = gbfw2[o];                   // LDS, not vmem
            float val = fmaxf(vp + gf.x, 0.f) * gf.y;
            if (((q & 1) == 0) && ((cx & 1) == 0)) preg[mf] += val;
        }
    }

    #pragma unroll
    for (int mf = 0; mf < 4; ++mf) {
        float v = preg[mf];
        v += __shfl_xor(v, 2);
        v += __shfl_xor(v, 4);
        v += __shfl_xor(v, 8);
        if (cx == 0 && (q & 1) == 0) {
            int bb = blockIdx.x*8 + mf*2 + (q >> 1);
            atomicAdd(&out[bb], v);
        }
    }
}

extern "C" void kernel_launch(void* const* d_in, const int* in_sizes, int n_in,
                              void* d_out, int out_size, void* d_ws, size_t ws_size,
                              hipStream_t stream)
{
    const int*   x   = (const int*)  d_in[0];
    const float* er  = (const float*)d_in[1];
    const float* ev  = (const float*)d_in[2];
    const float* cw  = (const float*)d_in[3];
    const float* cb  = (const float*)d_in[4];
    const float* gam = (const float*)d_in[5];
    const float* bet = (const float*)d_in[6];
    const float* gW  = (const float*)d_in[7];
    const float* gb  = (const float*)d_in[8];
    const float* fW  = (const float*)d_in[9];
    const float* fb  = (const float*)d_in[10];

    float* ws = (float*)d_ws;
    _Float16* m_raw = (_Float16*)(ws + MRAW_OFF);
    _Float16* W_h   = (_Float16*)(ws + WH_OFF);
    _Float16* wT    = (_Float16*)(ws + WT_OFF);
    float* gshad    = ws + STAT_OFF;
    float* scale    = gshad + 6400;
    float* shift    = scale + 200;
    float* out      = (float*)d_out;

    (void)hipMemsetAsync(gshad, 0, 16*400*sizeof(float), stream);

    k0_prep<<<(K0_TOT + 255)/256, 256, 0, stream>>>(cw, gW, fb, wT, W_h, out);
    k1_mfma<<<NROWS/32, 256, 0, stream>>>(x, er, ev, wT, cb, m_raw, gshad);
    k2_stats<<<1, 256, 0, stream>>>(gshad, gam, bet, scale, shift);
    k3_mfma<<<MPAD/64, 256, 0, stream>>>(m_raw, scale, shift, W_h, gb, fW, out);
}

// Round 10
// 83.457 us; speedup vs baseline: 1.1575x; 1.0789x over previous
//
#include <hip/hip_runtime.h>
#include <hip/hip_bf16.h>
#include <hip/hip_fp16.h>

#define B_    4096
#define ARITY 6
#define EMB   100
#define NF    200
#define FC    1200
#define NROWS (B_*ARITY)      // 24576
#define MPAD  (B_*8)          // 32768 padded M rows (8 per batch, 2 sentinel)
#define NPAD  2432            // N rows of W_h (A/C pairs interleaved)
#define BN_EPS 1e-5f
#define KP    224
#define SENT  32768.0f
#define NTW   (NPAD/4/16)     // 38 tiles of 16 N-rows per wave

typedef _Float16 half8 __attribute__((ext_vector_type(8)));
typedef float f32x4 __attribute__((ext_vector_type(4)));

// ws float offsets
#define MRAW_OFF 0              // m_raw f16 [24576][200] -> 2,457,600 f
#define WH_OFF   2457600        // W_h f16 [2432][224]    ->   272,384 f  (LINEAR, no swizzle)
#define WT_OFF   2729984        // wT  f16 [7][2][224][32] ->   50,176 f (swizzled, k1)
#define STAT_OFF 2780160        // gshad[16][400]

__device__ __forceinline__ void gload16(const void* g, void* l) {
    __builtin_amdgcn_global_load_lds(
        (const __attribute__((address_space(1))) void*)g,
        (__attribute__((address_space(3))) void*)l, 16, 0, 0);
}

__device__ __forceinline__ float4 ld4(const float* rr, const float* vr, int e) {
    if (e < EMB)        return *(const float4*)&rr[e];
    else if (e < 2*EMB) return *(const float4*)&vr[e - EMB];
    float4 z = {0.f,0.f,0.f,0.f}; return z;
}

// ---------------- k0: weight prep + out init -------------------------------
// wT (k1): swizzled [ks][hi|lo][224][32].  W_h (k3): LINEAR rows (direct
// global->VGPR loads in k3 need no bank swizzle).
#define K0_W1 (224*28)
#define K0_W2 (K0_W1 + NPAD*28)
#define K0_TOT (K0_W2 + B_)
__launch_bounds__(256)
__global__ void k0_prep(const float* __restrict__ cw, const float* __restrict__ gW,
                        const float* __restrict__ fb,
                        _Float16* __restrict__ wT,
                        _Float16* __restrict__ W_h, float* __restrict__ out)
{
    int id = blockIdx.x * 256 + threadIdx.x;
    if (id < K0_W1) {
        int f = id / 28, s = id - f*28;
        int ks = s >> 2, ls = s & 3, key = (f >> 1) & 3;
        int off = ks*14336 + f*32 + ((ls ^ key)*8);
        half8 h, l;
        #pragma unroll
        for (int j = 0; j < 8; ++j) {
            int k = s*8 + j;
            float v = (f < NF && k < NF) ? cw[f*NF + k] : 0.f;
            _Float16 hi = (_Float16)v;
            h[j] = hi; l[j] = (_Float16)(v - (float)hi);
        }
        *(half8*)&wT[off] = h;
        *(half8*)&wT[off + 7168] = l;
    } else if (id < K0_W2) {
        int id2 = id - K0_W1;
        int n = id2 / 28, s = id2 - n*28;
        int o = n >> 1, hf = n & 1;
        half8 h;
        #pragma unroll
        for (int j = 0; j < 8; ++j) {
            int k = s*8 + j;
            float v = 0.f;
            if (k < NF && n < 2*FC) v = gW[(size_t)o*400 + hf*200 + k];
            if (k == NF) v = SENT;           // sentinel column
            h[j] = (_Float16)v;
        }
        *(half8*)&W_h[(size_t)n*KP + s*8] = h;
    } else if (id < K0_TOT) {
        out[id - K0_W2] = fb[0];
    }
}

// ---------------- k1: gather + split-f16 MFMA conv + stats -----------------
// (unchanged from round 8/9 -- passing, fenced ring-2)
__launch_bounds__(256)
__global__ void k1_mfma(const int* __restrict__ x,
                        const float* __restrict__ er,
                        const float* __restrict__ ev,
                        const _Float16* __restrict__ wT,
                        const float* __restrict__ cb,
                        _Float16* __restrict__ m_raw,
                        float* __restrict__ gshad)
{
    __shared__ __align__(16) char smem[59200];
    float* s_sum = (float*)(smem + 57344);
    float* s_sq  = (float*)(smem + 58144);
    int*   s_ri  = (int*)(smem + 58944);
    int*   s_vi  = (int*)(smem + 59072);

    const int t = threadIdx.x, lane = t & 63, wave = t >> 6;
    const int wm = wave >> 1, wn = wave & 1;
    const int R0 = blockIdx.x * 32;
    const int q = lane >> 4, cx = lane & 15;
    const int rdsw = (q ^ ((cx >> 1) & 3)) * 8;

    if (t < 32) {
        int R = R0 + t, b = R / ARITY, a = R - b * ARITY;
        bool is64 = ((x[1] | x[3] | x[5] | x[7]) == 0);
        int base = b * (2*ARITY) + 2*a;
        s_ri[t] = is64 ? x[2*base]     : x[base];
        s_vi[t] = is64 ? x[2*base + 2] : x[base + 1];
    }
    if (t < NF) { s_sum[t] = 0.f; s_sq[t] = 0.f; }
    __syncthreads();

    // ---- build A panel (32 rows x 224, hi+lo) in buf0, swizzled ----
    {
        _Float16* s_ahi = (_Float16*)smem;          // 32x224
        _Float16* s_alo = s_ahi + 7168;
        for (int c = t; c < 896; c += 256) {
            int row = c / 28, s = c - row*28;
            int key = (row >> 1) & 3;
            int col = (s >> 2)*32 + ((s & 3) ^ key)*8;
            const float* rr = er + (size_t)s_ri[row] * EMB;
            const float* vr = ev + (size_t)s_vi[row] * EMB;
            int e0 = s*8;
            float4 v0 = ld4(rr, vr, e0);
            float4 v1 = ld4(rr, vr, e0 + 4);
            half8 hi, lo;
            hi[0]=(_Float16)v0.x; lo[0]=(_Float16)(v0.x-(float)hi[0]);
            hi[1]=(_Float16)v0.y; lo[1]=(_Float16)(v0.y-(float)hi[1]);
            hi[2]=(_Float16)v0.z; lo[2]=(_Float16)(v0.z-(float)hi[2]);
            hi[3]=(_Float16)v0.w; lo[3]=(_Float16)(v0.w-(float)hi[3]);
            hi[4]=(_Float16)v1.x; lo[4]=(_Float16)(v1.x-(float)hi[4]);
            hi[5]=(_Float16)v1.y; lo[5]=(_Float16)(v1.y-(float)hi[5]);
            hi[6]=(_Float16)v1.z; lo[6]=(_Float16)(v1.z-(float)hi[6]);
            hi[7]=(_Float16)v1.w; lo[7]=(_Float16)(v1.w-(float)hi[7]);
            *(half8*)&s_ahi[row*KP + col] = hi;
            *(half8*)&s_alo[row*KP + col] = lo;
        }
    }
    __syncthreads();

    // ---- hoist A fragments (1 mf x 7 ks, hi+lo) to registers ----
    f32x4 ah[7], al[7];
    {
        const _Float16* s_ahi = (const _Float16*)smem;
        const _Float16* s_alo = s_ahi + 7168;
        int arow = wm*16 + cx;
        #pragma unroll
        for (int ks = 0; ks < 7; ++ks) {
            ah[ks] = *(const f32x4*)&s_ahi[arow*KP + ks*32 + rdsw];
            al[ks] = *(const f32x4*)&s_alo[arow*KP + ks*32 + rdsw];
            asm volatile("" : "+v"(ah[ks]), "+v"(al[ks]));
        }
    }
    __syncthreads();   // A reads done; drains all vmem -> counts exact below

    #define STAGE_W(KS_, BUF_) do {                                          \
        const char* _src = (const char*)wT + (size_t)(KS_) * 28672;          \
        char* _dst = smem + (BUF_) * 28672;                                  \
        _Pragma("unroll")                                                    \
        for (int _i = 0; _i < 7; ++_i) {                                     \
            int _j = wave + 4*_i;                                            \
            gload16(_src + (size_t)(_j*64 + lane)*16, _dst + _j*1024);       \
        }                                                                    \
    } while (0)

    STAGE_W(0, 0);
    STAGE_W(1, 1);

    f32x4 acc[7];
    #pragma unroll
    for (int nf = 0; nf < 7; ++nf) acc[nf] = (f32x4){0.f,0.f,0.f,0.f};

    for (int ks = 0; ks < 7; ++ks) {
        if (ks < 6) asm volatile("s_waitcnt vmcnt(7)" ::: "memory");
        else        asm volatile("s_waitcnt vmcnt(0)" ::: "memory");
        __builtin_amdgcn_s_barrier();
        __builtin_amdgcn_sched_barrier(0);

        const _Float16* wb = (const _Float16*)(smem + (ks & 1) * 28672);
        #pragma unroll
        for (int nf = 0; nf < 7; ++nf) {
            int rb = (wn*112 + nf*16 + cx)*32 + rdsw;
            half8 bh = *(const half8*)&wb[rb];
            half8 bl = *(const half8*)&wb[7168 + rb];
            acc[nf] = __builtin_amdgcn_mfma_f32_16x16x32_f16(
                __builtin_bit_cast(half8, ah[ks]), bh, acc[nf], 0,0,0);
            acc[nf] = __builtin_amdgcn_mfma_f32_16x16x32_f16(
                __builtin_bit_cast(half8, ah[ks]), bl, acc[nf], 0,0,0);
            acc[nf] = __builtin_amdgcn_mfma_f32_16x16x32_f16(
                __builtin_bit_cast(half8, al[ks]), bh, acc[nf], 0,0,0);
        }
        // FENCE: own ds_reads complete, all waves past them, nothing moves
        // across -- only then may the stage overwrite this buffer.
        asm volatile("s_waitcnt lgkmcnt(0)" ::: "memory");
        __builtin_amdgcn_sched_barrier(0);
        __builtin_amdgcn_s_barrier();
        __builtin_amdgcn_sched_barrier(0);
        if (ks + 2 < 7) STAGE_W(ks + 2, ks & 1);
    }

    // epilogue: +bias, write m_raw (f16), block stats
    #pragma unroll
    for (int nf = 0; nf < 7; ++nf) {
        int f = wn*112 + nf*16 + cx;
        bool valid = (f < NF);
        float bias = valid ? cb[f] : 0.f;
        float ps = 0.f, pq = 0.f;
        #pragma unroll
        for (int reg = 0; reg < 4; ++reg) {
            float vv = acc[nf][reg] + bias;
            if (valid) {
                int R = R0 + wm*16 + q*4 + reg;
                m_raw[(size_t)R*NF + f] = (_Float16)vv;
                ps += vv; pq += vv*vv;
            }
        }
        ps += __shfl_xor(ps, 16); ps += __shfl_xor(ps, 32);
        pq += __shfl_xor(pq, 16); pq += __shfl_xor(pq, 32);
        if (valid && q == 0) { atomicAdd(&s_sum[f], ps); atomicAdd(&s_sq[f], pq); }
    }
    __syncthreads();
    if (t < NF) {
        float* g = gshad + (blockIdx.x & 15) * 400;
        atomicAdd(&g[t], s_sum[t]);
        atomicAdd(&g[t + 200], s_sq[t]);
    }
}

// ---------------- k3: wave-autonomous MFMA, B direct global->VGPR ----------
// Grid 512, 4 waves, block = 64 padded M rows (8 batches). Wave owns all 64
// M rows (av[4][7] in regs) x a private o-quarter (608 N-rows, 38 tiles of
// 16). B fragments load DIRECTLY global->VGPR (one f32x4 per lane per ks):
// no LDS staging, no fences, no barriers in the loop; compiler's register
// dependency tracking inserts the exact counted vmcnt. Static double-buffer
// bvA/bvB with unroll-by-2 (rule #20). BN stats finalize (old k2) inlined.
// LDS: A panel 28672 | gbfw2 9728 | scsh 1792 = 40192 B.
__launch_bounds__(256, 2)
__global__ void k3_mfma(const _Float16* __restrict__ m_raw,
                        const float* __restrict__ gshad,
                        const float* __restrict__ gamma,
                        const float* __restrict__ beta,
                        const _Float16* __restrict__ W_h,
                        const float* __restrict__ gb,
                        const float* __restrict__ fW,
                        float* __restrict__ out)
{
    __shared__ __align__(16) char smem[40192];
    float2* gbfw2 = (float2*)(smem + 28672);
    float*  scsh  = (float*)(smem + 28672 + 9728);

    const int t = threadIdx.x, lane = t & 63, wave = t >> 6;
    const int q = lane >> 4, cx = lane & 15;
    const int rdsw = (q ^ ((cx >> 1) & 3)) * 8;

    // ---- inlined k2: BN scale/shift from gshad ----
    if (t < 224) {
        float sc = 0.f, sh = 0.f;
        if (t < NF) {
            float s = 0.f, qq = 0.f;
            #pragma unroll
            for (int c = 0; c < 16; ++c) { s += gshad[c*400 + t]; qq += gshad[c*400 + 200 + t]; }
            float inv = 1.0f / (float)NROWS;
            float mu  = s * inv;
            float var = qq * inv - mu*mu;
            float rs  = rsqrtf(var + BN_EPS);
            sc = rs * gamma[t];
            sh = beta[t] - mu*sc;
        }
        scsh[t] = sc; scsh[224 + t] = sh;
    }
    for (int i = t; i < 1216; i += 256) {
        float g = (i < FC) ? gb[i] : 0.f;
        float f = (i < FC) ? fW[i] : 0.f;
        gbfw2[i] = make_float2(g, f);
    }
    __syncthreads();

    // ---- build padded+swizzled A panel (64 rows x 224 f16) ----
    {
        _Float16* sa = (_Float16*)smem;
        for (int c = t; c < 1792; c += 256) {          // 64 rows x 28 chunks
            int Rp = c / 28, s = c - Rp*28;
            int a = Rp & 7, b = Rp >> 3;
            int key = (Rp >> 1) & 3;
            int col = (s >> 2)*32 + ((s & 3) ^ key)*8;
            half8 o;
            #pragma unroll
            for (int j = 0; j < 8; ++j) o[j] = (_Float16)0.f;
            if (a < ARITY && s < 25) {
                int R = (blockIdx.x*8 + b)*ARITY + a;
                half8 in = *(const half8*)&m_raw[(size_t)R*NF + s*8];
                #pragma unroll
                for (int j = 0; j < 8; ++j) {
                    int k = s*8 + j;
                    o[j] = (_Float16)fmaxf((float)in[j]*scsh[k] + scsh[224+k], 0.f);
                }
            } else if (a >= ARITY && s == 25) {
                o[0] = (_Float16)1.0f;                 // k==200 sentinel unit
            }
            *(half8*)&sa[Rp*KP + col] = o;
        }
    }
    __syncthreads();

    // ---- hoist A fragments (4 mf x 7 ks) to registers: rows mf*16+cx ----
    f32x4 av[4][7];
    {
        const _Float16* sa = (const _Float16*)smem;
        #pragma unroll
        for (int mf = 0; mf < 4; ++mf) {
            int row = mf*16 + cx;
            #pragma unroll
            for (int ks = 0; ks < 7; ++ks) {
                av[mf][ks] = *(const f32x4*)&sa[row*KP + ks*32 + rdsw];
                asm volatile("" : "+v"(av[mf][ks]));   // force register residency
            }
        }
    }

    // ---- per-wave o-quarter, B direct to regs ----
    const int nbase = wave * (NPAD/4);                 // 608 N-rows per wave
    const char* wsrc = (const char*)(W_h + (size_t)nbase * KP);
    const int boff = cx*448 + q*16;                    // per-lane byte offset

    #define LOADT(BV_, NT_) do {                                             \
        const char* _b = wsrc + (size_t)(NT_)*7168 + boff;                   \
        _Pragma("unroll")                                                    \
        for (int _k = 0; _k < 7; ++_k)                                       \
            BV_[_k] = *(const f32x4*)(_b + _k*64);                           \
    } while (0)

    float preg[4] = {0.f, 0.f, 0.f, 0.f};

    #define TILE(BV_, NT_) do {                                              \
        f32x4 _acc[4];                                                       \
        _Pragma("unroll")                                                    \
        for (int _m = 0; _m < 4; ++_m) _acc[_m] = (f32x4){0.f,0.f,0.f,0.f};  \
        _Pragma("unroll")                                                    \
        for (int _k = 0; _k < 7; ++_k) {                                     \
            _Pragma("unroll")                                                \
            for (int _m = 0; _m < 4; ++_m)                                   \
                _acc[_m] = __builtin_amdgcn_mfma_f32_16x16x32_f16(           \
                    __builtin_bit_cast(half8, av[_m][_k]),                   \
                    __builtin_bit_cast(half8, BV_[_k]), _acc[_m], 0, 0, 0);  \
        }                                                                    \
        _Pragma("unroll")                                                    \
        for (int _m = 0; _m < 4; ++_m) {                                     \
            f32x4 _a4 = _acc[_m];                                            \
            float _v = fminf(fminf(_a4[0], _a4[1]), fminf(_a4[2], _a4[3]));  \
            _v = fminf(_v, __shfl_xor(_v, 16));     /* 8-row batch min */    \
            float _vp = _v + __shfl_xor(_v, 1);     /* A + C halves */       \
            int _o = (nbase + (NT_)*16 + cx) >> 1;                           \
            float2 _gf = gbfw2[_o];                                          \
            float _val = fmaxf(_vp + _gf.x, 0.f) * _gf.y;                    \
            if (((q & 1) == 0) && ((cx & 1) == 0)) preg[_m] += _val;         \
        }                                                                    \
    } while (0)

    f32x4 bvA[7], bvB[7];
    LOADT(bvA, 0);
    for (int nt = 0; nt < NTW; nt += 2) {
        LOADT(bvB, nt + 1);                 // nt+1 <= 37 always valid
        TILE(bvA, nt);
        if (nt + 2 < NTW) LOADT(bvA, nt + 2);
        TILE(bvB, nt + 1);
    }

    #pragma unroll
    for (int mf = 0; mf < 4; ++mf) {
        float v = preg[mf];
        v += __shfl_xor(v, 2);
        v += __shfl_xor(v, 4);
        v += __shfl_xor(v, 8);
        if (cx == 0 && (q & 1) == 0) {
            int bb = blockIdx.x*8 + mf*2 + (q >> 1);
            atomicAdd(&out[bb], v);
        }
    }
}

extern "C" void kernel_launch(void* const* d_in, const int* in_sizes, int n_in,
                              void* d_out, int out_size, void* d_ws, size_t ws_size,
                              hipStream_t stream)
{
    const int*   x   = (const int*)  d_in[0];
    const float* er  = (const float*)d_in[1];
    const float* ev  = (const float*)d_in[2];
    const float* cw  = (const float*)d_in[3];
    const float* cb  = (const float*)d_in[4];
    const float* gam = (const float*)d_in[5];
    const float* bet = (const float*)d_in[6];
    const float* gW  = (const float*)d_in[7];
    const float* gb  = (const float*)d_in[8];
    const float* fW  = (const float*)d_in[9];
    const float* fb  = (const float*)d_in[10];

    float* ws = (float*)d_ws;
    _Float16* m_raw = (_Float16*)(ws + MRAW_OFF);
    _Float16* W_h   = (_Float16*)(ws + WH_OFF);
    _Float16* wT    = (_Float16*)(ws + WT_OFF);
    float* gshad    = ws + STAT_OFF;
    float* out      = (float*)d_out;

    (void)hipMemsetAsync(gshad, 0, 16*400*sizeof(float), stream);

    k0_prep<<<(K0_TOT + 255)/256, 256, 0, stream>>>(cw, gW, fb, wT, W_h, out);
    k1_mfma<<<NROWS/32, 256, 0, stream>>>(x, er, ev, wT, cb, m_raw, gshad);
    k3_mfma<<<MPAD/64, 256, 0, stream>>>(m_raw, gshad, gam, bet, W_h, gb, fW, out);
}